// Round 1
// baseline (488.463 us; speedup 1.0000x reference)
//
#include <hip/hip_runtime.h>
#include <hip/hip_bf16.h>
#include <cstdint>

// ---------------------------------------------------------------------------
// LinearMultiHeadAttention: B=4, S=4096, D_MODEL=1024, H=16, Dk=64
// out = (q @ E_t^T) where E_t[b][j][hd] = scale * sum_e kv[b,h,d,e]*W_o[j,h*64+e]
//       kv[b,h] = k^T v  (sum over s), q/k/v = x @ W^T
// ---------------------------------------------------------------------------

typedef __bf16 bf16x8 __attribute__((ext_vector_type(8)));
typedef float f32x4 __attribute__((ext_vector_type(4)));
typedef unsigned short ushort_t;

__device__ inline void gld_lds16(const void* g, void* l) {
    __builtin_amdgcn_global_load_lds(
        (const __attribute__((address_space(1))) unsigned int*)g,
        (__attribute__((address_space(3))) unsigned int*)l,
        16, 0, 0);
}

__device__ inline ushort_t f2bf(float f) {
    uint32_t u = __float_as_uint(f);
    uint32_t r = (u + 0x7fffu + ((u >> 16) & 1u)) >> 16;
    return (ushort_t)r;
}

// ---------------------------------------------------------------------------
// C = A @ B^T   A:[M,K] bf16, B:[N,K] bf16, C:[M,N] (OutT = ushort bf16 or float)
// 128x128 block tile, BK=32, 4 waves each 64x64 (4x4 of 16x16x32 MFMA).
// M%128==0, N%128==0, K%32==0 assumed.
// ---------------------------------------------------------------------------
template <typename OutT>
__global__ __launch_bounds__(256, 2)
void gemm_bt(const ushort_t* __restrict__ A, const ushort_t* __restrict__ B,
             OutT* __restrict__ C, int M, int N, int K,
             long strideA, long strideB, long strideC)
{
    __shared__ ushort_t lA[128 * 32];
    __shared__ ushort_t lB[128 * 32];

    const int t    = threadIdx.x;
    const int lane = t & 63;
    const int wid  = t >> 6;

    A += (size_t)blockIdx.z * strideA;
    B += (size_t)blockIdx.z * strideB;
    C += (size_t)blockIdx.z * strideC;

    const int m0 = blockIdx.x * 128;
    const int n0 = blockIdx.y * 128;

    const int wm = (wid >> 1) * 64;   // wave's m offset in tile
    const int wn = (wid & 1) * 64;    // wave's n offset in tile
    const int mr = lane & 15;
    const int q4 = lane >> 4;

    // staging: thread t covers 16B chunk idx=t (+256): row=idx>>2, seg=(idx&3)*8 elems
    const int row_a = t >> 2;          // 0..63
    const int seg   = (t & 3) * 8;     // element offset in row

    f32x4 acc[4][4] = {};

    for (int k0 = 0; k0 < K; k0 += 32) {
        __syncthreads();
        gld_lds16(A + (size_t)(m0 + row_a) * K + k0 + seg,       (char*)lA + wid * 1024);
        gld_lds16(A + (size_t)(m0 + 64 + row_a) * K + k0 + seg,  (char*)lA + 4096 + wid * 1024);
        gld_lds16(B + (size_t)(n0 + row_a) * K + k0 + seg,       (char*)lB + wid * 1024);
        gld_lds16(B + (size_t)(n0 + 64 + row_a) * K + k0 + seg,  (char*)lB + 4096 + wid * 1024);
        __syncthreads();

        bf16x8 af[4], bf[4];
#pragma unroll
        for (int i = 0; i < 4; ++i)
            af[i] = *(const bf16x8*)((const char*)lA + (wm + i * 16 + mr) * 64 + q4 * 16);
#pragma unroll
        for (int j = 0; j < 4; ++j)
            bf[j] = *(const bf16x8*)((const char*)lB + (wn + j * 16 + mr) * 64 + q4 * 16);
#pragma unroll
        for (int i = 0; i < 4; ++i)
#pragma unroll
            for (int j = 0; j < 4; ++j)
                acc[i][j] = __builtin_amdgcn_mfma_f32_16x16x32_bf16(af[i], bf[j], acc[i][j], 0, 0, 0);
    }

    // epilogue: D row = quad*4+reg (m), col = lane&15 (n)
#pragma unroll
    for (int i = 0; i < 4; ++i) {
        const int rbase = m0 + wm + i * 16 + q4 * 4;
#pragma unroll
        for (int j = 0; j < 4; ++j) {
            const int col = n0 + wn + j * 16 + mr;
#pragma unroll
            for (int r = 0; r < 4; ++r) {
                const float v = acc[i][j][r];
                const size_t off = (size_t)(rbase + r) * N + col;
                if constexpr (sizeof(OutT) == 2) C[off] = f2bf(v);
                else                             C[off] = v;
            }
        }
    }
}

// ---------------------------------------------------------------------------
// kv[b,h,d,e] += sum_{s in split} k[b,s,h,d]*v[b,s,h,e]
// grid (16 splits, 64 bh); 256 threads; thread owns 4x4 (d,e) block.
// ---------------------------------------------------------------------------
__global__ __launch_bounds__(256)
void kv_kernel(const ushort_t* __restrict__ Kb, const ushort_t* __restrict__ Vb,
               float* __restrict__ KV)
{
    __shared__ ushort_t sK[32 * 64];
    __shared__ ushort_t sV[32 * 64];

    const int t  = threadIdx.x;
    const int bh = blockIdx.y;           // b*16+h
    const int b  = bh >> 4, h = bh & 15;
    const int s_base = blockIdx.x * 256;

    const ushort_t* Kp = Kb + (size_t)(b * 4096) * 1024 + h * 64;
    const ushort_t* Vp = Vb + (size_t)(b * 4096) * 1024 + h * 64;

    const int d0 = (t >> 4) * 4;
    const int e0 = (t & 15) * 4;
    float acc[4][4] = {};

    const int lrow = t >> 3;             // 0..31
    const int lcol = (t & 7) * 8;        // 0..56

    for (int c = 0; c < 8; ++c) {
        const int s0 = s_base + c * 32;
        __syncthreads();
        *(uint4*)&sK[lrow * 64 + lcol] = *(const uint4*)&Kp[(size_t)(s0 + lrow) * 1024 + lcol];
        *(uint4*)&sV[lrow * 64 + lcol] = *(const uint4*)&Vp[(size_t)(s0 + lrow) * 1024 + lcol];
        __syncthreads();
#pragma unroll 8
        for (int s = 0; s < 32; ++s) {
            const uint2 kk = *(const uint2*)&sK[s * 64 + d0];
            const uint2 vv = *(const uint2*)&sV[s * 64 + e0];
            float kd[4], ve[4];
            kd[0] = __uint_as_float(kk.x << 16);
            kd[1] = __uint_as_float(kk.x & 0xffff0000u);
            kd[2] = __uint_as_float(kk.y << 16);
            kd[3] = __uint_as_float(kk.y & 0xffff0000u);
            ve[0] = __uint_as_float(vv.x << 16);
            ve[1] = __uint_as_float(vv.x & 0xffff0000u);
            ve[2] = __uint_as_float(vv.y << 16);
            ve[3] = __uint_as_float(vv.y & 0xffff0000u);
#pragma unroll
            for (int i = 0; i < 4; ++i)
#pragma unroll
                for (int j = 0; j < 4; ++j)
                    acc[i][j] += kd[i] * ve[j];
        }
    }

    float* kvp = KV + ((size_t)bh * 64) * 64;
#pragma unroll
    for (int i = 0; i < 4; ++i)
#pragma unroll
        for (int j = 0; j < 4; ++j)
            atomicAdd(&kvp[(d0 + i) * 64 + e0 + j], acc[i][j]);
}

// ---------------------------------------------------------------------------
// E_t[b][j][hd] = scale * sum_e kv[b,h,d,e] * W_o[j, h*64+e]   (bf16 out)
// grid (4 hd-blocks, 1024 j, 4 b); 256 threads
// ---------------------------------------------------------------------------
__global__ __launch_bounds__(256)
void make_E(const float* __restrict__ KV, const float* __restrict__ Wo,
            ushort_t* __restrict__ Et)
{
    __shared__ float sW[256];
    const int t = threadIdx.x;
    const int b = blockIdx.z, j = blockIdx.y;
    const int col0 = blockIdx.x * 256;
    const int hd = col0 + t;
    const int h = hd >> 6, d = hd & 63;

    sW[t] = Wo[(size_t)j * 1024 + col0 + t];
    __syncthreads();

    const float* kvp = KV + ((size_t)(b * 16 + h) * 64 + d) * 64;
    const float* wp  = &sW[(t >> 6) * 64];
    float sum = 0.f;
#pragma unroll 16
    for (int e = 0; e < 64; ++e) sum += kvp[e] * wp[e];
    Et[((size_t)b * 1024 + j) * 1024 + hd] = f2bf(sum * 0.125f);
}

// ---------------------------------------------------------------------------
// fp32 -> bf16 cast, 4 elems/thread (n % 4 == 0)
// ---------------------------------------------------------------------------
__global__ __launch_bounds__(256)
void cast_bf16(const float* __restrict__ in, ushort_t* __restrict__ out, int n)
{
    const int i = (blockIdx.x * 256 + threadIdx.x) * 4;
    if (i >= n) return;
    const float4 f = *(const float4*)&in[i];
    ushort_t o0 = f2bf(f.x), o1 = f2bf(f.y), o2 = f2bf(f.z), o3 = f2bf(f.w);
    ushort4 o; o.x = o0; o.y = o1; o.z = o2; o.w = o3;
    *(ushort4*)&out[i] = o;
}

// ---------------------------------------------------------------------------

extern "C" void kernel_launch(void* const* d_in, const int* in_sizes, int n_in,
                              void* d_out, int out_size, void* d_ws, size_t ws_size,
                              hipStream_t stream)
{
    const float* x  = (const float*)d_in[0];
    const float* Wq = (const float*)d_in[1];
    const float* Wk = (const float*)d_in[2];
    const float* Wv = (const float*)d_in[3];
    const float* Wo = (const float*)d_in[4];
    float* out = (float*)d_out;

    const int B = 4, S = 4096, D = 1024, H = 16, Dk = 64;
    const int M = B * S;                 // 16384

    char* ws = (char*)d_ws;
    size_t off = 0;
    auto alloc = [&](size_t bytes) -> void* {
        void* p = ws + off;
        off += (bytes + 255) & ~(size_t)255;
        return p;
    };
    ushort_t* xb  = (ushort_t*)alloc((size_t)M * D * 2);     // 33.5 MB (reused for Et)
    ushort_t* qb  = (ushort_t*)alloc((size_t)M * D * 2);
    ushort_t* kb  = (ushort_t*)alloc((size_t)M * D * 2);
    ushort_t* vb  = (ushort_t*)alloc((size_t)M * D * 2);
    ushort_t* wqb = (ushort_t*)alloc((size_t)D * D * 2);
    ushort_t* wkb = (ushort_t*)alloc((size_t)D * D * 2);
    ushort_t* wvb = (ushort_t*)alloc((size_t)D * D * 2);
    float*    kvb = (float*)alloc((size_t)B * H * Dk * Dk * 4);  // 1 MB
    ushort_t* Et  = xb;   // alias: xb dead after projections, Et written after kv

    // casts
    cast_bf16<<<dim3((M * D) / 4 / 256), dim3(256), 0, stream>>>(x,  xb,  M * D);
    cast_bf16<<<dim3((D * D) / 4 / 256), dim3(256), 0, stream>>>(Wq, wqb, D * D);
    cast_bf16<<<dim3((D * D) / 4 / 256), dim3(256), 0, stream>>>(Wk, wkb, D * D);
    cast_bf16<<<dim3((D * D) / 4 / 256), dim3(256), 0, stream>>>(Wv, wvb, D * D);

    // projections: [16384,1024] @ [1024,1024]^T -> bf16
    dim3 pg(M / 128, D / 128, 1);
    gemm_bt<ushort_t><<<pg, dim3(256), 0, stream>>>(xb, wqb, qb, M, D, D, 0, 0, 0);
    gemm_bt<ushort_t><<<pg, dim3(256), 0, stream>>>(xb, wkb, kb, M, D, D, 0, 0, 0);
    gemm_bt<ushort_t><<<pg, dim3(256), 0, stream>>>(xb, wvb, vb, M, D, D, 0, 0, 0);

    // kv = k^T v per (b,h)
    hipMemsetAsync(kvb, 0, (size_t)B * H * Dk * Dk * 4, stream);
    kv_kernel<<<dim3(16, B * H), dim3(256), 0, stream>>>(kb, vb, kvb);

    // E_t[b][j][hd]
    make_E<<<dim3(4, 1024, B), dim3(256), 0, stream>>>(kvb, Wo, Et);

    // out[b] = q[b] @ E_t[b]^T  -> fp32
    gemm_bt<float><<<dim3(S / 128, D / 128, B), dim3(256), 0, stream>>>(
        qb, Et, out, S, D, D, (long)S * D, (long)D * D, (long)S * D);
}

// Round 2
// 401.987 us; speedup vs baseline: 1.2151x; 1.2151x over previous
//
#include <hip/hip_runtime.h>
#include <hip/hip_bf16.h>
#include <cstdint>

// ---------------------------------------------------------------------------
// LinearMultiHeadAttention: B=4, S=4096, D_MODEL=1024, H=16, Dk=64
// qkv = x @ Wqkv^T (fused N=3072); kv[b,h] = k^T v;
// E_t[b][j][hd] = scale * sum_e kv[b,h,d,e]*W_o[j,h*64+e];  out = q @ E_t^T
// ---------------------------------------------------------------------------

typedef __bf16 bf16x8 __attribute__((ext_vector_type(8)));
typedef float f32x4 __attribute__((ext_vector_type(4)));
typedef unsigned short ushort_t;

__device__ inline void gld_lds16(const void* g, void* l) {
    __builtin_amdgcn_global_load_lds(
        (const __attribute__((address_space(1))) unsigned int*)g,
        (__attribute__((address_space(3))) unsigned int*)l,
        16, 0, 0);
}

__device__ inline ushort_t f2bf(float f) {
    uint32_t u = __float_as_uint(f);
    uint32_t r = (u + 0x7fffu + ((u >> 16) & 1u)) >> 16;
    return (ushort_t)r;
}

// ---------------------------------------------------------------------------
// C = A @ B^T   A:[M,K] bf16 (row pitch lda), B:[N,K] bf16 (pitch ldb),
// C:[M,N] (pitch ldc). 128x128 tile, BK=32, 4 waves of 64x64 (4x4 16x16x32).
// grid.x = M/128, grid.y = N/128, grid.z = batch.
// ---------------------------------------------------------------------------
template <typename OutT>
__global__ __launch_bounds__(256, 2)
void gemm_bt(const ushort_t* __restrict__ A, int lda, long strideA,
             const ushort_t* __restrict__ B, int ldb, long strideB,
             OutT* __restrict__ C, int ldc, long strideC, int K)
{
    __shared__ ushort_t lA[128 * 32];
    __shared__ ushort_t lB[128 * 32];

    const int t    = threadIdx.x;
    const int lane = t & 63;
    const int wid  = t >> 6;

    A += (size_t)blockIdx.z * strideA;
    B += (size_t)blockIdx.z * strideB;
    C += (size_t)blockIdx.z * strideC;

    const int m0 = blockIdx.x * 128;
    const int n0 = blockIdx.y * 128;

    const int wm = (wid >> 1) * 64;
    const int wn = (wid & 1) * 64;
    const int mr = lane & 15;
    const int q4 = lane >> 4;

    const int row_a = t >> 2;          // 0..63
    const int seg   = (t & 3) * 8;     // element offset in row

    f32x4 acc[4][4] = {};

    for (int k0 = 0; k0 < K; k0 += 32) {
        __syncthreads();
        gld_lds16(A + (size_t)(m0 + row_a) * lda + k0 + seg,      (char*)lA + wid * 1024);
        gld_lds16(A + (size_t)(m0 + 64 + row_a) * lda + k0 + seg, (char*)lA + 4096 + wid * 1024);
        gld_lds16(B + (size_t)(n0 + row_a) * ldb + k0 + seg,      (char*)lB + wid * 1024);
        gld_lds16(B + (size_t)(n0 + 64 + row_a) * ldb + k0 + seg, (char*)lB + 4096 + wid * 1024);
        __syncthreads();

        bf16x8 af[4], bf[4];
#pragma unroll
        for (int i = 0; i < 4; ++i)
            af[i] = *(const bf16x8*)((const char*)lA + (wm + i * 16 + mr) * 64 + q4 * 16);
#pragma unroll
        for (int j = 0; j < 4; ++j)
            bf[j] = *(const bf16x8*)((const char*)lB + (wn + j * 16 + mr) * 64 + q4 * 16);
#pragma unroll
        for (int i = 0; i < 4; ++i)
#pragma unroll
            for (int j = 0; j < 4; ++j)
                acc[i][j] = __builtin_amdgcn_mfma_f32_16x16x32_bf16(af[i], bf[j], acc[i][j], 0, 0, 0);
    }

#pragma unroll
    for (int i = 0; i < 4; ++i) {
        const int rbase = m0 + wm + i * 16 + q4 * 4;
#pragma unroll
        for (int j = 0; j < 4; ++j) {
            const int col = n0 + wn + j * 16 + mr;
#pragma unroll
            for (int r = 0; r < 4; ++r) {
                const float v = acc[i][j][r];
                const size_t off = (size_t)(rbase + r) * ldc + col;
                if constexpr (sizeof(OutT) == 2) C[off] = f2bf(v);
                else                             C[off] = v;
            }
        }
    }
}

// ---------------------------------------------------------------------------
// kv[b,h,d,e] += sum_{s in split} k[b,s,h,d]*v[b,s,h,e]
// K/V live inside the fused qkv buffer with row pitch ld.
// grid (16 splits, 64 bh); 256 threads; thread owns 4x4 (d,e) block.
// ---------------------------------------------------------------------------
__global__ __launch_bounds__(256)
void kv_kernel(const ushort_t* __restrict__ Kb, const ushort_t* __restrict__ Vb,
               int ld, float* __restrict__ KV)
{
    __shared__ ushort_t sK[32 * 64];
    __shared__ ushort_t sV[32 * 64];

    const int t  = threadIdx.x;
    const int bh = blockIdx.y;           // b*16+h
    const int b  = bh >> 4, h = bh & 15;
    const int s_base = blockIdx.x * 256;

    const ushort_t* Kp = Kb + (size_t)(b * 4096) * ld + h * 64;
    const ushort_t* Vp = Vb + (size_t)(b * 4096) * ld + h * 64;

    const int d0 = (t >> 4) * 4;
    const int e0 = (t & 15) * 4;
    float acc[4][4] = {};

    const int lrow = t >> 3;             // 0..31
    const int lcol = (t & 7) * 8;        // 0..56

    for (int c = 0; c < 8; ++c) {
        const int s0 = s_base + c * 32;
        __syncthreads();
        *(uint4*)&sK[lrow * 64 + lcol] = *(const uint4*)&Kp[(size_t)(s0 + lrow) * ld + lcol];
        *(uint4*)&sV[lrow * 64 + lcol] = *(const uint4*)&Vp[(size_t)(s0 + lrow) * ld + lcol];
        __syncthreads();
#pragma unroll 8
        for (int s = 0; s < 32; ++s) {
            const uint2 kk = *(const uint2*)&sK[s * 64 + d0];
            const uint2 vv = *(const uint2*)&sV[s * 64 + e0];
            float kd[4], ve[4];
            kd[0] = __uint_as_float(kk.x << 16);
            kd[1] = __uint_as_float(kk.x & 0xffff0000u);
            kd[2] = __uint_as_float(kk.y << 16);
            kd[3] = __uint_as_float(kk.y & 0xffff0000u);
            ve[0] = __uint_as_float(vv.x << 16);
            ve[1] = __uint_as_float(vv.x & 0xffff0000u);
            ve[2] = __uint_as_float(vv.y << 16);
            ve[3] = __uint_as_float(vv.y & 0xffff0000u);
#pragma unroll
            for (int i = 0; i < 4; ++i)
#pragma unroll
                for (int j = 0; j < 4; ++j)
                    acc[i][j] += kd[i] * ve[j];
        }
    }

    float* kvp = KV + ((size_t)bh * 64) * 64;
#pragma unroll
    for (int i = 0; i < 4; ++i)
#pragma unroll
        for (int j = 0; j < 4; ++j)
            atomicAdd(&kvp[(d0 + i) * 64 + e0 + j], acc[i][j]);
}

// ---------------------------------------------------------------------------
// E_t[b][j][h*64+d] = scale * sum_e kv[b,h,d,e] * W_o[j, h*64+e]   (bf16 out)
// grid (16 j-chunks of 64, 64 bh); 256 threads.
// LDS: kv[b,h] 64x64 (pitch 65) + Wo slice 64x64 (pitch 65).
// Thread t: d-group d0=(t&15)*4, jloc=(t>>4) + pass*16, 4 passes.
// ---------------------------------------------------------------------------
__global__ __launch_bounds__(256)
void make_E(const float* __restrict__ KV, const float* __restrict__ Wo,
            ushort_t* __restrict__ Et)
{
    __shared__ float skv[64 * 65];
    __shared__ float swo[64 * 65];

    const int t  = threadIdx.x;
    const int bh = blockIdx.y;
    const int b  = bh >> 4, h = bh & 15;
    const int j0 = blockIdx.x * 64;

    const float* kvp = KV + (size_t)bh * 4096;
#pragma unroll
    for (int i = 0; i < 4; ++i) {
        const int idx = t + i * 256;          // float4 index 0..1023
        const int r = idx >> 4, c = (idx & 15) * 4;
        const float4 f = *(const float4*)&kvp[r * 64 + c];
        skv[r * 65 + c + 0] = f.x;
        skv[r * 65 + c + 1] = f.y;
        skv[r * 65 + c + 2] = f.z;
        skv[r * 65 + c + 3] = f.w;
        const float4 g = *(const float4*)&Wo[(size_t)(j0 + r) * 1024 + h * 64 + c];
        swo[r * 65 + c + 0] = g.x;
        swo[r * 65 + c + 1] = g.y;
        swo[r * 65 + c + 2] = g.z;
        swo[r * 65 + c + 3] = g.w;
    }
    __syncthreads();

    const int d0 = (t & 15) * 4;
#pragma unroll
    for (int pass = 0; pass < 4; ++pass) {
        const int jloc = (t >> 4) + pass * 16;
        float s0 = 0.f, s1 = 0.f, s2 = 0.f, s3 = 0.f;
        const float* wrow = &swo[jloc * 65];
#pragma unroll 8
        for (int e = 0; e < 64; ++e) {
            const float w = wrow[e];
            s0 += skv[(d0 + 0) * 65 + e] * w;
            s1 += skv[(d0 + 1) * 65 + e] * w;
            s2 += skv[(d0 + 2) * 65 + e] * w;
            s3 += skv[(d0 + 3) * 65 + e] * w;
        }
        ushort4 o;
        o.x = f2bf(s0 * 0.125f);
        o.y = f2bf(s1 * 0.125f);
        o.z = f2bf(s2 * 0.125f);
        o.w = f2bf(s3 * 0.125f);
        *(ushort4*)&Et[((size_t)b * 1024 + j0 + jloc) * 1024 + h * 64 + d0] = o;
    }
}

// ---------------------------------------------------------------------------
// fp32 -> bf16 cast, 4 elems/thread (n % 1024 == 0)
// ---------------------------------------------------------------------------
__global__ __launch_bounds__(256)
void cast_bf16(const float* __restrict__ in, ushort_t* __restrict__ out, int n)
{
    const int i = (blockIdx.x * 256 + threadIdx.x) * 4;
    if (i >= n) return;
    const float4 f = *(const float4*)&in[i];
    ushort4 o;
    o.x = f2bf(f.x); o.y = f2bf(f.y); o.z = f2bf(f.z); o.w = f2bf(f.w);
    *(ushort4*)&out[i] = o;
}

// ---------------------------------------------------------------------------

extern "C" void kernel_launch(void* const* d_in, const int* in_sizes, int n_in,
                              void* d_out, int out_size, void* d_ws, size_t ws_size,
                              hipStream_t stream)
{
    const float* x  = (const float*)d_in[0];
    const float* Wq = (const float*)d_in[1];
    const float* Wk = (const float*)d_in[2];
    const float* Wv = (const float*)d_in[3];
    const float* Wo = (const float*)d_in[4];
    float* out = (float*)d_out;

    const int B = 4, S = 4096, D = 1024, H = 16, Dk = 64;
    const int M  = B * S;            // 16384
    const int N3 = 3 * D;            // 3072

    char* ws = (char*)d_ws;
    size_t off = 0;
    auto alloc = [&](size_t bytes) -> void* {
        void* p = ws + off;
        off += (bytes + 255) & ~(size_t)255;
        return p;
    };
    ushort_t* xb   = (ushort_t*)alloc((size_t)M * D * 2);       // 33.5 MB (reused for Et)
    ushort_t* qkv  = (ushort_t*)alloc((size_t)M * N3 * 2);      // 100.7 MB
    ushort_t* wqkv = (ushort_t*)alloc((size_t)N3 * D * 2);      // 6.3 MB
    float*    kvb  = (float*)alloc((size_t)B * H * Dk * Dk * 4);// 1 MB
    ushort_t* Et   = xb;   // alias: xb dead after QKV GEMM

    // casts: x -> bf16; Wq/Wk/Wv -> concatenated [3072,1024] bf16
    cast_bf16<<<dim3((M * D) / 4 / 256), dim3(256), 0, stream>>>(x,  xb, M * D);
    cast_bf16<<<dim3((D * D) / 4 / 256), dim3(256), 0, stream>>>(Wq, wqkv,             D * D);
    cast_bf16<<<dim3((D * D) / 4 / 256), dim3(256), 0, stream>>>(Wk, wqkv + D * D,     D * D);
    cast_bf16<<<dim3((D * D) / 4 / 256), dim3(256), 0, stream>>>(Wv, wqkv + 2 * D * D, D * D);

    // fused QKV projection: [16384,1024] @ [3072,1024]^T -> [16384,3072] bf16
    gemm_bt<ushort_t><<<dim3(M / 128, N3 / 128, 1), dim3(256), 0, stream>>>(
        xb, D, 0, wqkv, D, 0, qkv, N3, 0, D);

    // kv = k^T v per (b,h); k = qkv cols [1024,2048), v = [2048,3072)
    hipMemsetAsync(kvb, 0, (size_t)B * H * Dk * Dk * 4, stream);
    kv_kernel<<<dim3(16, B * H), dim3(256), 0, stream>>>(qkv + D, qkv + 2 * D, N3, kvb);

    // E_t
    make_E<<<dim3(16, B * H), dim3(256), 0, stream>>>(kvb, Wo, Et);

    // out[b] = q[b] @ E_t[b]^T -> fp32; q = qkv cols [0,1024)
    gemm_bt<float><<<dim3(S / 128, D / 128, B), dim3(256), 0, stream>>>(
        qkv, N3, (long)S * N3, Et, D, (long)D * D, out, D, (long)S * D, D);
}

// Round 3
// 368.937 us; speedup vs baseline: 1.3240x; 1.0896x over previous
//
#include <hip/hip_runtime.h>
#include <hip/hip_bf16.h>
#include <cstdint>

// ---------------------------------------------------------------------------
// LinearMultiHeadAttention: B=4, S=4096, D_MODEL=1024, H=16, Dk=64
// qkv = x @ Wqkv^T (fused N=3072, C split into q-slab + kv-slab);
// kv[b,h] = k^T v (split partials, no atomics);
// E_t[b][j][hd] = scale * sum_e kv[b,h,d,e]*W_o[j,h*64+e];  out = q @ E_t^T
//
// LDS XOR swizzle in gemm_bt: chunk c of row r stored at c ^ ((r>>1)&3)
// -> fragment ds_read_b128 is 2-way (free) instead of 8-way bank aliasing.
// ---------------------------------------------------------------------------

typedef __bf16 bf16x8 __attribute__((ext_vector_type(8)));
typedef float f32x4 __attribute__((ext_vector_type(4)));
typedef unsigned short ushort_t;

__device__ inline void gld_lds16(const void* g, void* l) {
    __builtin_amdgcn_global_load_lds(
        (const __attribute__((address_space(1))) unsigned int*)g,
        (__attribute__((address_space(3))) unsigned int*)l,
        16, 0, 0);
}

__device__ inline ushort_t f2bf(float f) {
    uint32_t u = __float_as_uint(f);
    uint32_t r = (u + 0x7fffu + ((u >> 16) & 1u)) >> 16;
    return (ushort_t)r;
}

// ---------------------------------------------------------------------------
// C = A @ B^T   A:[M,K] bf16 (pitch lda), B:[N,K] bf16 (pitch ldb).
// Output columns [0,nsplit) -> C0 (pitch ldc0), [nsplit,N) -> C1 (pitch ldc1).
// 128x128 tile, BK=32, 4 waves of 64x64 (4x4 16x16x32 MFMA).
// ---------------------------------------------------------------------------
template <typename OutT>
__global__ __launch_bounds__(256, 2)
void gemm_bt(const ushort_t* __restrict__ A, int lda, long strideA,
             const ushort_t* __restrict__ B, int ldb, long strideB,
             OutT* __restrict__ C0, int ldc0, long strideC0,
             OutT* __restrict__ C1, int ldc1, long strideC1, int nsplit,
             int K)
{
    __shared__ ushort_t lA[128 * 32];
    __shared__ ushort_t lB[128 * 32];

    const int t    = threadIdx.x;
    const int lane = t & 63;
    const int wid  = t >> 6;

    A += (size_t)blockIdx.z * strideA;
    B += (size_t)blockIdx.z * strideB;

    const int m0 = blockIdx.x * 128;
    const int n0 = blockIdx.y * 128;

    const int wm = (wid >> 1) * 64;
    const int wn = (wid & 1) * 64;
    const int mr = lane & 15;
    const int q4 = lane >> 4;

    // staging: thread t covers LDS chunk t (16B): row = t>>2, lds chunk c = t&3,
    // which must hold GLOBAL chunk c ^ ((row>>1)&3)   [(row>>1)&3 == (t>>3)&3]
    const int row_a = t >> 2;                              // 0..63
    const int seg   = ((t & 3) ^ ((t >> 3) & 3)) * 8;      // swizzled elem offset

    // fragment read: lane (mr,q4) wants global chunk q4 of its rows; rows are
    // E + mr with E%16==0 and (E>>1)%4==0, so stored chunk = q4 ^ ((mr>>1)&3)
    const int csw = (q4 ^ ((mr >> 1) & 3)) * 16;           // byte offset in row

    f32x4 acc[4][4] = {};

    for (int k0 = 0; k0 < K; k0 += 32) {
        __syncthreads();
        gld_lds16(A + (size_t)(m0 + row_a) * lda + k0 + seg,      (char*)lA + wid * 1024);
        gld_lds16(A + (size_t)(m0 + 64 + row_a) * lda + k0 + seg, (char*)lA + 4096 + wid * 1024);
        gld_lds16(B + (size_t)(n0 + row_a) * ldb + k0 + seg,      (char*)lB + wid * 1024);
        gld_lds16(B + (size_t)(n0 + 64 + row_a) * ldb + k0 + seg, (char*)lB + 4096 + wid * 1024);
        __syncthreads();

        bf16x8 af[4], bf[4];
#pragma unroll
        for (int i = 0; i < 4; ++i)
            af[i] = *(const bf16x8*)((const char*)lA + (wm + i * 16 + mr) * 64 + csw);
#pragma unroll
        for (int j = 0; j < 4; ++j)
            bf[j] = *(const bf16x8*)((const char*)lB + (wn + j * 16 + mr) * 64 + csw);
#pragma unroll
        for (int i = 0; i < 4; ++i)
#pragma unroll
            for (int j = 0; j < 4; ++j)
                acc[i][j] = __builtin_amdgcn_mfma_f32_16x16x32_bf16(af[i], bf[j], acc[i][j], 0, 0, 0);
    }

    // pick output slab (whole 128-tile lies on one side; nsplit % 128 == 0)
    OutT* Cw; int ldcw, nc0;
    if (n0 < nsplit) { Cw = C0 + (size_t)blockIdx.z * strideC0; ldcw = ldc0; nc0 = n0; }
    else             { Cw = C1 + (size_t)blockIdx.z * strideC1; ldcw = ldc1; nc0 = n0 - nsplit; }

#pragma unroll
    for (int i = 0; i < 4; ++i) {
        const int rbase = m0 + wm + i * 16 + q4 * 4;
#pragma unroll
        for (int j = 0; j < 4; ++j) {
            const int col = nc0 + wn + j * 16 + mr;
#pragma unroll
            for (int r = 0; r < 4; ++r) {
                const float v = acc[i][j][r];
                const size_t off = (size_t)(rbase + r) * ldcw + col;
                if constexpr (sizeof(OutT) == 2) Cw[off] = f2bf(v);
                else                             Cw[off] = v;
            }
        }
    }
}

// ---------------------------------------------------------------------------
// Partial kv: KVp[split][bh][d][e] = sum_{s in split} k[b,s,h,d]*v[b,s,h,e]
// K/V interleaved in kv-slab (pitch ld): k at col h*64, v at col 1024+h*64.
// grid (16 splits, 64 bh); 256 threads; thread owns 4x4 (d,e); plain stores.
// ---------------------------------------------------------------------------
__global__ __launch_bounds__(256)
void kv_kernel(const ushort_t* __restrict__ KVslab, int ld,
               float* __restrict__ KVp)
{
    __shared__ ushort_t sK[32 * 64];
    __shared__ ushort_t sV[32 * 64];

    const int t  = threadIdx.x;
    const int bh = blockIdx.y;           // b*16+h
    const int b  = bh >> 4, h = bh & 15;
    const int s_base = blockIdx.x * 256;

    const ushort_t* Kp = KVslab + (size_t)(b * 4096) * ld + h * 64;
    const ushort_t* Vp = Kp + 1024;

    const int d0 = (t >> 4) * 4;
    const int e0 = (t & 15) * 4;
    float acc[4][4] = {};

    const int lrow = t >> 3;             // 0..31
    const int lcol = (t & 7) * 8;        // 0..56

    for (int c = 0; c < 8; ++c) {
        const int s0 = s_base + c * 32;
        __syncthreads();
        *(uint4*)&sK[lrow * 64 + lcol] = *(const uint4*)&Kp[(size_t)(s0 + lrow) * ld + lcol];
        *(uint4*)&sV[lrow * 64 + lcol] = *(const uint4*)&Vp[(size_t)(s0 + lrow) * ld + lcol];
        __syncthreads();
#pragma unroll 8
        for (int s = 0; s < 32; ++s) {
            const uint2 kk = *(const uint2*)&sK[s * 64 + d0];
            const uint2 vv = *(const uint2*)&sV[s * 64 + e0];
            float kd[4], ve[4];
            kd[0] = __uint_as_float(kk.x << 16);
            kd[1] = __uint_as_float(kk.x & 0xffff0000u);
            kd[2] = __uint_as_float(kk.y << 16);
            kd[3] = __uint_as_float(kk.y & 0xffff0000u);
            ve[0] = __uint_as_float(vv.x << 16);
            ve[1] = __uint_as_float(vv.x & 0xffff0000u);
            ve[2] = __uint_as_float(vv.y << 16);
            ve[3] = __uint_as_float(vv.y & 0xffff0000u);
#pragma unroll
            for (int i = 0; i < 4; ++i)
#pragma unroll
                for (int j = 0; j < 4; ++j)
                    acc[i][j] += kd[i] * ve[j];
        }
    }

    float* outp = KVp + ((size_t)(blockIdx.x * 64 + bh)) * 4096;
#pragma unroll
    for (int i = 0; i < 4; ++i) {
        float4 o; o.x = acc[i][0]; o.y = acc[i][1]; o.z = acc[i][2]; o.w = acc[i][3];
        *(float4*)&outp[(d0 + i) * 64 + e0] = o;
    }
}

// ---------------------------------------------------------------------------
// KV[bh][i] = sum_{s<16} KVp[s][bh][i]   (64*4096 floats = 65536 float4s)
// ---------------------------------------------------------------------------
__global__ __launch_bounds__(256)
void reduce_kv(const float4* __restrict__ in, float4* __restrict__ out)
{
    const int i = blockIdx.x * 256 + threadIdx.x;   // 0..65535
    float4 a = in[i];
#pragma unroll
    for (int s = 1; s < 16; ++s) {
        const float4 b = in[s * 65536 + i];
        a.x += b.x; a.y += b.y; a.z += b.z; a.w += b.w;
    }
    out[i] = a;
}

// ---------------------------------------------------------------------------
// E_t[b][j][h*64+d] = scale * sum_e kv[b,h,d,e] * W_o[j, h*64+e]   (bf16 out)
// grid (16 j-chunks of 64, 64 bh); 256 threads.
// ---------------------------------------------------------------------------
__global__ __launch_bounds__(256)
void make_E(const float* __restrict__ KV, const float* __restrict__ Wo,
            ushort_t* __restrict__ Et)
{
    __shared__ float skv[64 * 65];
    __shared__ float swo[64 * 65];

    const int t  = threadIdx.x;
    const int bh = blockIdx.y;
    const int b  = bh >> 4, h = bh & 15;
    const int j0 = blockIdx.x * 64;

    const float* kvp = KV + (size_t)bh * 4096;
#pragma unroll
    for (int i = 0; i < 4; ++i) {
        const int idx = t + i * 256;          // float4 index 0..1023
        const int r = idx >> 4, c = (idx & 15) * 4;
        const float4 f = *(const float4*)&kvp[r * 64 + c];
        skv[r * 65 + c + 0] = f.x;
        skv[r * 65 + c + 1] = f.y;
        skv[r * 65 + c + 2] = f.z;
        skv[r * 65 + c + 3] = f.w;
        const float4 g = *(const float4*)&Wo[(size_t)(j0 + r) * 1024 + h * 64 + c];
        swo[r * 65 + c + 0] = g.x;
        swo[r * 65 + c + 1] = g.y;
        swo[r * 65 + c + 2] = g.z;
        swo[r * 65 + c + 3] = g.w;
    }
    __syncthreads();

    const int d0 = (t & 15) * 4;
#pragma unroll
    for (int pass = 0; pass < 4; ++pass) {
        const int jloc = (t >> 4) + pass * 16;
        float s0 = 0.f, s1 = 0.f, s2 = 0.f, s3 = 0.f;
        const float* wrow = &swo[jloc * 65];
#pragma unroll 8
        for (int e = 0; e < 64; ++e) {
            const float w = wrow[e];
            s0 += skv[(d0 + 0) * 65 + e] * w;
            s1 += skv[(d0 + 1) * 65 + e] * w;
            s2 += skv[(d0 + 2) * 65 + e] * w;
            s3 += skv[(d0 + 3) * 65 + e] * w;
        }
        ushort4 o;
        o.x = f2bf(s0 * 0.125f);
        o.y = f2bf(s1 * 0.125f);
        o.z = f2bf(s2 * 0.125f);
        o.w = f2bf(s3 * 0.125f);
        *(ushort4*)&Et[((size_t)b * 1024 + j0 + jloc) * 1024 + h * 64 + d0] = o;
    }
}

// ---------------------------------------------------------------------------
// casts
// ---------------------------------------------------------------------------
__global__ __launch_bounds__(256)
void cast_bf16(const float* __restrict__ in, ushort_t* __restrict__ out, int n)
{
    const int i = (blockIdx.x * 256 + threadIdx.x) * 4;
    if (i >= n) return;
    const float4 f = *(const float4*)&in[i];
    ushort4 o;
    o.x = f2bf(f.x); o.y = f2bf(f.y); o.z = f2bf(f.z); o.w = f2bf(f.w);
    *(ushort4*)&out[i] = o;
}

__global__ __launch_bounds__(256)
void cast_w3(const float* __restrict__ a, const float* __restrict__ b,
             const float* __restrict__ c, ushort_t* __restrict__ out)
{
    const float* src = (blockIdx.y == 0) ? a : (blockIdx.y == 1) ? b : c;
    const int i = (blockIdx.x * 256 + threadIdx.x) * 4;
    const float4 f = *(const float4*)&src[i];
    ushort4 o;
    o.x = f2bf(f.x); o.y = f2bf(f.y); o.z = f2bf(f.z); o.w = f2bf(f.w);
    *(ushort4*)&out[(size_t)blockIdx.y * 1048576 + i] = o;
}

// ---------------------------------------------------------------------------

extern "C" void kernel_launch(void* const* d_in, const int* in_sizes, int n_in,
                              void* d_out, int out_size, void* d_ws, size_t ws_size,
                              hipStream_t stream)
{
    const float* x  = (const float*)d_in[0];
    const float* Wq = (const float*)d_in[1];
    const float* Wk = (const float*)d_in[2];
    const float* Wv = (const float*)d_in[3];
    const float* Wo = (const float*)d_in[4];
    float* out = (float*)d_out;

    const int B = 4, S = 4096, D = 1024;
    const int M  = B * S;            // 16384
    const int N3 = 3 * D;            // 3072

    char* ws = (char*)d_ws;
    size_t off = 0;
    auto alloc = [&](size_t bytes) -> void* {
        void* p = ws + off;
        off += (bytes + 255) & ~(size_t)255;
        return p;
    };
    ushort_t* xb     = (ushort_t*)alloc((size_t)M * D * 2);        // 33.5 MB
    ushort_t* qb     = (ushort_t*)alloc((size_t)M * D * 2);        // 33.5 MB
    ushort_t* kvslab = (ushort_t*)alloc((size_t)M * 2 * D * 2);    // 67.1 MB
    ushort_t* wqkv   = (ushort_t*)alloc((size_t)N3 * D * 2);       // 6.3 MB
    float*    kvr    = (float*)alloc((size_t)64 * 4096 * 4);       // 1 MB reduced kv
    // aliases onto xb (dead after QKV GEMM):
    float*    kvp = (float*)xb;   // 16 splits x 64 bh x 4096 = 16 MB partials
    ushort_t* Et  = xb;           // written by make_E after reduce_kv consumed kvp

    // casts: x -> bf16; Wq/Wk/Wv -> concatenated [3072,1024] bf16
    cast_bf16<<<dim3((M * D) / 4 / 256), dim3(256), 0, stream>>>(x, xb, M * D);
    cast_w3<<<dim3((D * D) / 4 / 256, 3), dim3(256), 0, stream>>>(Wq, Wk, Wv, wqkv);

    // fused QKV projection: cols [0,1024) -> qb (pitch 1024), [1024,3072) -> kvslab (pitch 2048)
    gemm_bt<ushort_t><<<dim3(M / 128, N3 / 128, 1), dim3(256), 0, stream>>>(
        xb, D, 0, wqkv, D, 0,
        qb, D, 0, kvslab, 2 * D, 0, D, D);

    // kv partials: k at kvslab col 0, v at col 1024 (per-head offsets inside)
    kv_kernel<<<dim3(16, 64), dim3(256), 0, stream>>>(kvslab, 2 * D, kvp);
    reduce_kv<<<dim3(256), dim3(256), 0, stream>>>((const float4*)kvp, (float4*)kvr);

    // E_t
    make_E<<<dim3(16, 64), dim3(256), 0, stream>>>(kvr, Wo, Et);

    // out[b] = q[b] @ E_t[b]^T -> fp32
    gemm_bt<float><<<dim3(S / 128, D / 128, B), dim3(256), 0, stream>>>(
        qb, D, (long)S * D, Et, D, (long)D * D,
        out, D, (long)S * D, (float*)nullptr, 0, 0, 1 << 30, D);
}

// Round 4
// 339.485 us; speedup vs baseline: 1.4388x; 1.0868x over previous
//
#include <hip/hip_runtime.h>
#include <hip/hip_bf16.h>
#include <cstdint>

// ---------------------------------------------------------------------------
// LinearMultiHeadAttention: B=4, S=4096, D_MODEL=1024, H=16, Dk=64
// Gram-path restructure:
//   G[b]  = x[b]^T x[b]                       (split-K=4 MFMA GEMM, bf16 partials)
//   H[b]  = Wk @ G[b]        (G symmetric)    (MFMA GEMM)
//   kv[b,h] = H_h @ Wv_h^T                    (small VALU kernel, i-split)
//   E_t[b][j][hd] = scale*sum_e kv*Wo         (make_E)
//   F[b]  = E_t[b] @ Wq                       (MFMA GEMM via Wq^T)
//   out   = x @ F[b]^T                        (MFMA GEMM)
// Eliminates q/k/v projections entirely (137.4 -> 86 GF, -200 MB HBM).
// ---------------------------------------------------------------------------

typedef __bf16 bf16x8 __attribute__((ext_vector_type(8)));
typedef float f32x4 __attribute__((ext_vector_type(4)));
typedef unsigned short ushort_t;

__device__ inline void gld_lds16(const void* g, void* l) {
    __builtin_amdgcn_global_load_lds(
        (const __attribute__((address_space(1))) unsigned int*)g,
        (__attribute__((address_space(3))) unsigned int*)l,
        16, 0, 0);
}

__device__ inline ushort_t f2bf(float f) {
    uint32_t u = __float_as_uint(f);
    uint32_t r = (u + 0x7fffu + ((u >> 16) & 1u)) >> 16;
    return (ushort_t)r;
}
__device__ inline float bf2f(ushort_t u) {
    return __uint_as_float((uint32_t)u << 16);
}

// ---------------------------------------------------------------------------
// C = A @ B^T. 128x128 tile, BK=32, XOR-swizzled LDS (conflict-free).
// kslices: blockIdx.z = b*kslices + ks; A/B get +b*stride + ks*K columns;
// C slab index = blockIdx.z (so split-K partials land in separate slabs).
// ---------------------------------------------------------------------------
template <typename OutT>
__global__ __launch_bounds__(256, 2)
void gemm_bt(const ushort_t* __restrict__ A, int lda, long strideA,
             const ushort_t* __restrict__ B, int ldb, long strideB,
             OutT* __restrict__ C0, int ldc0, long strideC0,
             OutT* __restrict__ C1, int ldc1, long strideC1, int nsplit,
             int K, int kslices)
{
    __shared__ ushort_t lA[128 * 32];
    __shared__ ushort_t lB[128 * 32];

    const int t    = threadIdx.x;
    const int lane = t & 63;
    const int wid  = t >> 6;

    const int z = blockIdx.z;
    int bb, ks;
    if (kslices == 4) { bb = z >> 2; ks = z & 3; }
    else              { bb = z;      ks = 0;     }

    A += (size_t)bb * strideA + (size_t)ks * K;
    B += (size_t)bb * strideB + (size_t)ks * K;

    const int m0 = blockIdx.x * 128;
    const int n0 = blockIdx.y * 128;

    const int wm = (wid >> 1) * 64;
    const int wn = (wid & 1) * 64;
    const int mr = lane & 15;
    const int q4 = lane >> 4;

    const int row_a = t >> 2;                              // 0..63
    const int seg   = ((t & 3) ^ ((t >> 3) & 3)) * 8;      // swizzled elem offset
    const int csw   = (q4 ^ ((mr >> 1) & 3)) * 16;         // swizzled read offset

    f32x4 acc[4][4] = {};

    for (int k0 = 0; k0 < K; k0 += 32) {
        __syncthreads();
        gld_lds16(A + (size_t)(m0 + row_a) * lda + k0 + seg,      (char*)lA + wid * 1024);
        gld_lds16(A + (size_t)(m0 + 64 + row_a) * lda + k0 + seg, (char*)lA + 4096 + wid * 1024);
        gld_lds16(B + (size_t)(n0 + row_a) * ldb + k0 + seg,      (char*)lB + wid * 1024);
        gld_lds16(B + (size_t)(n0 + 64 + row_a) * ldb + k0 + seg, (char*)lB + 4096 + wid * 1024);
        __syncthreads();

        bf16x8 af[4], bf[4];
#pragma unroll
        for (int i = 0; i < 4; ++i)
            af[i] = *(const bf16x8*)((const char*)lA + (wm + i * 16 + mr) * 64 + csw);
#pragma unroll
        for (int j = 0; j < 4; ++j)
            bf[j] = *(const bf16x8*)((const char*)lB + (wn + j * 16 + mr) * 64 + csw);
#pragma unroll
        for (int i = 0; i < 4; ++i)
#pragma unroll
            for (int j = 0; j < 4; ++j)
                acc[i][j] = __builtin_amdgcn_mfma_f32_16x16x32_bf16(af[i], bf[j], acc[i][j], 0, 0, 0);
    }

    OutT* Cw; int ldcw, nc0;
    if (n0 < nsplit) { Cw = C0 + (size_t)z * strideC0; ldcw = ldc0; nc0 = n0; }
    else             { Cw = C1 + (size_t)z * strideC1; ldcw = ldc1; nc0 = n0 - nsplit; }

#pragma unroll
    for (int i = 0; i < 4; ++i) {
        const int rbase = m0 + wm + i * 16 + q4 * 4;
#pragma unroll
        for (int j = 0; j < 4; ++j) {
            const int col = nc0 + wn + j * 16 + mr;
#pragma unroll
            for (int r = 0; r < 4; ++r) {
                const float v = acc[i][j][r];
                const size_t off = (size_t)(rbase + r) * ldcw + col;
                if constexpr (sizeof(OutT) == 2) Cw[off] = f2bf(v);
                else                             Cw[off] = v;
            }
        }
    }
}

// ---------------------------------------------------------------------------
// cast x fp32 [16384][1024] -> xb bf16 (same layout) + xbT bf16 [1024][16384].
// 64x64 tiles; LDS pitch 66 (2-way reads = free; uint-pair writes stay aligned).
// ---------------------------------------------------------------------------
__global__ __launch_bounds__(256)
void cast_x_t(const float* __restrict__ x, ushort_t* __restrict__ xb,
              ushort_t* __restrict__ xbT)
{
    __shared__ ushort_t lt[64 * 66];
    const int t  = threadIdx.x;
    const int s0 = blockIdx.x * 64;
    const int i0 = blockIdx.y * 64;

#pragma unroll
    for (int c = 0; c < 4; ++c) {
        const int idx = c * 256 + t;
        const int r = idx >> 4, c4 = (idx & 15) * 4;
        const float4 f = *(const float4*)&x[(size_t)(s0 + r) * 1024 + i0 + c4];
        ushort4 o;
        o.x = f2bf(f.x); o.y = f2bf(f.y); o.z = f2bf(f.z); o.w = f2bf(f.w);
        *(ushort4*)&xb[(size_t)(s0 + r) * 1024 + i0 + c4] = o;
        *(uint32_t*)&lt[r * 66 + c4]     = (uint32_t)o.x | ((uint32_t)o.y << 16);
        *(uint32_t*)&lt[r * 66 + c4 + 2] = (uint32_t)o.z | ((uint32_t)o.w << 16);
    }
    __syncthreads();
#pragma unroll
    for (int c = 0; c < 4; ++c) {
        const int idx = c * 256 + t;
        const int ri = idx >> 4, s4 = (idx & 15) * 4;
        ushort4 o;
        o.x = lt[(s4 + 0) * 66 + ri];
        o.y = lt[(s4 + 1) * 66 + ri];
        o.z = lt[(s4 + 2) * 66 + ri];
        o.w = lt[(s4 + 3) * 66 + ri];
        *(ushort4*)&xbT[(size_t)(i0 + ri) * 16384 + s0 + s4] = o;
    }
}

// ---------------------------------------------------------------------------
// cast+transpose Wq fp32 [1024][1024] -> wqT bf16 [1024][1024] (wqT[i][hd]=Wq[hd][i])
// ---------------------------------------------------------------------------
__global__ __launch_bounds__(256)
void cast_wt(const float* __restrict__ W, ushort_t* __restrict__ WT)
{
    __shared__ ushort_t lt[64 * 66];
    const int t  = threadIdx.x;
    const int r0 = blockIdx.x * 64;   // hd rows in
    const int c0 = blockIdx.y * 64;   // i cols in

#pragma unroll
    for (int c = 0; c < 4; ++c) {
        const int idx = c * 256 + t;
        const int r = idx >> 4, c4 = (idx & 15) * 4;
        const float4 f = *(const float4*)&W[(size_t)(r0 + r) * 1024 + c0 + c4];
        ushort4 o;
        o.x = f2bf(f.x); o.y = f2bf(f.y); o.z = f2bf(f.z); o.w = f2bf(f.w);
        *(uint32_t*)&lt[r * 66 + c4]     = (uint32_t)o.x | ((uint32_t)o.y << 16);
        *(uint32_t*)&lt[r * 66 + c4 + 2] = (uint32_t)o.z | ((uint32_t)o.w << 16);
    }
    __syncthreads();
#pragma unroll
    for (int c = 0; c < 4; ++c) {
        const int idx = c * 256 + t;
        const int ri = idx >> 4, s4 = (idx & 15) * 4;
        ushort4 o;
        o.x = lt[(s4 + 0) * 66 + ri];
        o.y = lt[(s4 + 1) * 66 + ri];
        o.z = lt[(s4 + 2) * 66 + ri];
        o.w = lt[(s4 + 3) * 66 + ri];
        *(ushort4*)&WT[(size_t)(c0 + ri) * 1024 + r0 + s4] = o;
    }
}

// ---------------------------------------------------------------------------
// plain cast Wk/Wv fp32 -> bf16; blockIdx.y selects src, out slabs adjacent
// ---------------------------------------------------------------------------
__global__ __launch_bounds__(256)
void cast_w2(const float* __restrict__ a, const float* __restrict__ b,
             ushort_t* __restrict__ out)
{
    const float* src = (blockIdx.y == 0) ? a : b;
    const int i = (blockIdx.x * 256 + threadIdx.x) * 4;
    const float4 f = *(const float4*)&src[i];
    ushort4 o;
    o.x = f2bf(f.x); o.y = f2bf(f.y); o.z = f2bf(f.z); o.w = f2bf(f.w);
    *(ushort4*)&out[(size_t)blockIdx.y * 1048576 + i] = o;
}

// ---------------------------------------------------------------------------
// reduce split-K=4 bf16 partial G slabs -> G bf16 [b][1024*1024]
// gid indexes ushort4 units; b = gid>>18.
// ---------------------------------------------------------------------------
__global__ __launch_bounds__(256)
void reduce_g(const ushort4* __restrict__ Gp, ushort4* __restrict__ G)
{
    const int gid = blockIdx.x * 256 + threadIdx.x;   // 0 .. 4*262144-1
    const int b = gid >> 18, r = gid & 262143;
    float s0 = 0.f, s1 = 0.f, s2 = 0.f, s3 = 0.f;
#pragma unroll
    for (int ks = 0; ks < 4; ++ks) {
        const ushort4 u = Gp[(size_t)(b * 4 + ks) * 262144 + r];
        s0 += bf2f(u.x); s1 += bf2f(u.y); s2 += bf2f(u.z); s3 += bf2f(u.w);
    }
    ushort4 o;
    o.x = f2bf(s0); o.y = f2bf(s1); o.z = f2bf(s2); o.w = f2bf(s3);
    G[gid] = o;
}

// ---------------------------------------------------------------------------
// kv partials: KVp[is][bh][d][e] = sum_{i in 128-slice} H[b][h64+d][i]*Wv[h64+e][i]
// grid (8 is, 64 bh); LDS pitch 132 (uint2-aligned; sV reads 4-way, acceptable).
// ---------------------------------------------------------------------------
__global__ __launch_bounds__(256)
void kvblk(const ushort_t* __restrict__ H, const ushort_t* __restrict__ Wv,
           float* __restrict__ KVp)
{
    __shared__ ushort_t sH[64 * 132];
    __shared__ ushort_t sV[64 * 132];

    const int t  = threadIdx.x;
    const int is = blockIdx.x;
    const int bh = blockIdx.y;
    const int b  = bh >> 4, h = bh & 15;

    const ushort_t* Hp = H + ((size_t)b << 20) + (size_t)(h * 64) * 1024 + is * 128;
    const ushort_t* Vp = Wv + (size_t)(h * 64) * 1024 + is * 128;

#pragma unroll
    for (int i2 = 0; i2 < 8; ++i2) {
        const int ci = i2 * 256 + t;
        const int r = ci >> 5, c = (ci & 31) * 4;
        *(uint2*)&sH[r * 132 + c] = *(const uint2*)&Hp[(size_t)r * 1024 + c];
        *(uint2*)&sV[r * 132 + c] = *(const uint2*)&Vp[(size_t)r * 1024 + c];
    }
    __syncthreads();

    const int d0 = (t >> 4) * 4;
    const int e0 = (t & 15) * 4;
    float acc[4][4] = {};

#pragma unroll 2
    for (int i4 = 0; i4 < 128; i4 += 4) {
        uint2 hu[4], vu[4];
#pragma unroll
        for (int j = 0; j < 4; ++j) {
            hu[j] = *(const uint2*)&sH[(d0 + j) * 132 + i4];
            vu[j] = *(const uint2*)&sV[(e0 + j) * 132 + i4];
        }
        float hf[4][4], vf[4][4];
#pragma unroll
        for (int j = 0; j < 4; ++j) {
            hf[j][0] = __uint_as_float(hu[j].x << 16);
            hf[j][1] = __uint_as_float(hu[j].x & 0xffff0000u);
            hf[j][2] = __uint_as_float(hu[j].y << 16);
            hf[j][3] = __uint_as_float(hu[j].y & 0xffff0000u);
            vf[j][0] = __uint_as_float(vu[j].x << 16);
            vf[j][1] = __uint_as_float(vu[j].x & 0xffff0000u);
            vf[j][2] = __uint_as_float(vu[j].y << 16);
            vf[j][3] = __uint_as_float(vu[j].y & 0xffff0000u);
        }
#pragma unroll
        for (int ii = 0; ii < 4; ++ii)
#pragma unroll
            for (int di = 0; di < 4; ++di)
#pragma unroll
                for (int ej = 0; ej < 4; ++ej)
                    acc[di][ej] += hf[di][ii] * vf[ej][ii];
    }

    float* outp = KVp + ((size_t)(is * 64 + bh)) * 4096;
#pragma unroll
    for (int i = 0; i < 4; ++i) {
        float4 o; o.x = acc[i][0]; o.y = acc[i][1]; o.z = acc[i][2]; o.w = acc[i][3];
        *(float4*)&outp[(d0 + i) * 64 + e0] = o;
    }
}

// ---------------------------------------------------------------------------
// KV[bh][i] = sum_{is<8} KVp[is][bh][i]   (64*4096 floats = 65536 float4)
// ---------------------------------------------------------------------------
__global__ __launch_bounds__(256)
void reduce_kv8(const float4* __restrict__ in, float4* __restrict__ out)
{
    const int i = blockIdx.x * 256 + threadIdx.x;   // 0..65535
    float4 a = in[i];
#pragma unroll
    for (int s = 1; s < 8; ++s) {
        const float4 b = in[s * 65536 + i];
        a.x += b.x; a.y += b.y; a.z += b.z; a.w += b.w;
    }
    out[i] = a;
}

// ---------------------------------------------------------------------------
// E_t[b][j][h*64+d] = scale * sum_e kv[b,h,d,e] * W_o[j, h*64+e]   (bf16 out)
// grid (16 j-chunks of 64, 64 bh); 256 threads.
// ---------------------------------------------------------------------------
__global__ __launch_bounds__(256)
void make_E(const float* __restrict__ KV, const float* __restrict__ Wo,
            ushort_t* __restrict__ Et)
{
    __shared__ float skv[64 * 65];
    __shared__ float swo[64 * 65];

    const int t  = threadIdx.x;
    const int bh = blockIdx.y;
    const int b  = bh >> 4, h = bh & 15;
    const int j0 = blockIdx.x * 64;

    const float* kvp = KV + (size_t)bh * 4096;
#pragma unroll
    for (int i = 0; i < 4; ++i) {
        const int idx = t + i * 256;
        const int r = idx >> 4, c = (idx & 15) * 4;
        const float4 f = *(const float4*)&kvp[r * 64 + c];
        skv[r * 65 + c + 0] = f.x;
        skv[r * 65 + c + 1] = f.y;
        skv[r * 65 + c + 2] = f.z;
        skv[r * 65 + c + 3] = f.w;
        const float4 g = *(const float4*)&Wo[(size_t)(j0 + r) * 1024 + h * 64 + c];
        swo[r * 65 + c + 0] = g.x;
        swo[r * 65 + c + 1] = g.y;
        swo[r * 65 + c + 2] = g.z;
        swo[r * 65 + c + 3] = g.w;
    }
    __syncthreads();

    const int d0 = (t & 15) * 4;
#pragma unroll
    for (int pass = 0; pass < 4; ++pass) {
        const int jloc = (t >> 4) + pass * 16;
        float s0 = 0.f, s1 = 0.f, s2 = 0.f, s3 = 0.f;
        const float* wrow = &swo[jloc * 65];
#pragma unroll 8
        for (int e = 0; e < 64; ++e) {
            const float w = wrow[e];
            s0 += skv[(d0 + 0) * 65 + e] * w;
            s1 += skv[(d0 + 1) * 65 + e] * w;
            s2 += skv[(d0 + 2) * 65 + e] * w;
            s3 += skv[(d0 + 3) * 65 + e] * w;
        }
        ushort4 o;
        o.x = f2bf(s0 * 0.125f);
        o.y = f2bf(s1 * 0.125f);
        o.z = f2bf(s2 * 0.125f);
        o.w = f2bf(s3 * 0.125f);
        *(ushort4*)&Et[((size_t)b * 1024 + j0 + jloc) * 1024 + h * 64 + d0] = o;
    }
}

// ---------------------------------------------------------------------------

extern "C" void kernel_launch(void* const* d_in, const int* in_sizes, int n_in,
                              void* d_out, int out_size, void* d_ws, size_t ws_size,
                              hipStream_t stream)
{
    const float* x  = (const float*)d_in[0];
    const float* Wq = (const float*)d_in[1];
    const float* Wk = (const float*)d_in[2];
    const float* Wv = (const float*)d_in[3];
    const float* Wo = (const float*)d_in[4];
    float* out = (float*)d_out;

    const int B = 4, S = 4096, D = 1024;
    const long MB1 = 1048576;

    char* ws = (char*)d_ws;
    size_t off = 0;
    auto alloc = [&](size_t bytes) -> void* {
        void* p = ws + off;
        off += (bytes + 255) & ~(size_t)255;
        return p;
    };
    ushort_t* xb   = (ushort_t*)alloc((size_t)B * S * D * 2);      // 33.5 MB
    ushort_t* xbT  = (ushort_t*)alloc((size_t)D * B * S * 2);      // 33.5 MB [i][b*4096+s]
    ushort_t* wkv  = (ushort_t*)alloc((size_t)2 * D * D * 2);      // wk | wv
    ushort_t* wqT  = (ushort_t*)alloc((size_t)D * D * 2);
    ushort_t* Gb   = (ushort_t*)alloc((size_t)B * D * D * 2);      // 8.4 MB
    float*    kvp  = (float*)alloc((size_t)8 * 64 * 4096 * 4);     // 8.4 MB
    float*    kvr  = (float*)alloc((size_t)64 * 4096 * 4);         // 1 MB
    char*     R1   = (char*)alloc((size_t)16 * MB1 * 2);           // 33.5 MB shared
    ushort_t* Gp = (ushort_t*)R1;                    // [16][1M] bf16 partials
    ushort_t* Hb = (ushort_t*)R1;                    // [4][1M] (Gp dead)
    ushort_t* Et = (ushort_t*)(R1 + 8 * MB1 * 2);    // [4][1M] (disjoint from Hb)
    ushort_t* Fb = (ushort_t*)(R1 + 16 * MB1 * 2 - 8 * MB1 * 2); // last 8.4 MB
    ushort_t* wkb = wkv;
    ushort_t* wvb = wkv + MB1;

    // casts
    cast_x_t<<<dim3(256, 16), dim3(256), 0, stream>>>(x, xb, xbT);
    cast_w2<<<dim3(1024, 2), dim3(256), 0, stream>>>(Wk, Wv, wkv);
    cast_wt<<<dim3(16, 16), dim3(256), 0, stream>>>(Wq, wqT);

    // G[b] = x^T x, split-K=4: A=B=xbT (lda 16384), z = b*4+ks -> slab Gp[z]
    gemm_bt<ushort_t><<<dim3(8, 8, 16), dim3(256), 0, stream>>>(
        xbT, 16384, 4096, xbT, 16384, 4096,
        Gp, D, MB1, (ushort_t*)nullptr, 0, 0, 1 << 30, D, 4);
    reduce_g<<<dim3(4096), dim3(256), 0, stream>>>((const ushort4*)Gp, (ushort4*)Gb);

    // H[b] = Wk @ G[b]  (G symmetric -> use G as B directly)
    gemm_bt<ushort_t><<<dim3(8, 8, 4), dim3(256), 0, stream>>>(
        wkb, D, 0, Gb, D, MB1,
        Hb, D, MB1, (ushort_t*)nullptr, 0, 0, 1 << 30, D, 1);

    // kv[b,h] = H_h @ Wv_h^T (i-split 8) + reduce
    kvblk<<<dim3(8, 64), dim3(256), 0, stream>>>(Hb, wvb, kvp);
    reduce_kv8<<<dim3(256), dim3(256), 0, stream>>>((const float4*)kvp, (float4*)kvr);

    // E_t
    make_E<<<dim3(16, 64), dim3(256), 0, stream>>>(kvr, Wo, Et);

    // F[b] = E_t[b] @ Wq  (B = wqT, shared)
    gemm_bt<ushort_t><<<dim3(8, 8, 4), dim3(256), 0, stream>>>(
        Et, D, MB1, wqT, D, 0,
        Fb, D, MB1, (ushort_t*)nullptr, 0, 0, 1 << 30, D, 1);

    // out[b] = x[b] @ F[b]^T -> fp32
    gemm_bt<float><<<dim3(32, 8, 4), dim3(256), 0, stream>>>(
        xb, D, (long)S * D, Fb, D, MB1,
        out, D, (long)S * D, (float*)nullptr, 0, 0, 1 << 30, D, 1);
}

// Round 6
// 315.607 us; speedup vs baseline: 1.5477x; 1.0757x over previous
//
#include <hip/hip_runtime.h>
#include <hip/hip_bf16.h>
#include <cstdint>

// ---------------------------------------------------------------------------
// LinearMultiHeadAttention: B=4, S=4096, D_MODEL=1024, H=16, Dk=64
// Gram-path:
//   G[b]  = x[b]^T x[b]     (SYMMETRIC: upper-triangle tiles only, split-K=4)
//   H[b]  = Wk @ G[b]
//   kv[b,h] = H_h @ Wv_h^T
//   E_t[b][j][hd] = scale*sum_e kv*Wo
//   F[b]  = E_t[b] @ Wq
//   out   = x @ F[b]^T
// R6 fixes vs R5: reduce_g_t grid covers all 16x16 64-tiles (was 8x8 -> 3/4 of
// G stale); Fb gets its own slab (was aliased onto Et -> read/write race).
// ---------------------------------------------------------------------------

typedef __bf16 bf16x8 __attribute__((ext_vector_type(8)));
typedef float f32x4 __attribute__((ext_vector_type(4)));
typedef unsigned short ushort_t;

__device__ inline void gld_lds16(const void* g, void* l) {
    __builtin_amdgcn_global_load_lds(
        (const __attribute__((address_space(1))) unsigned int*)g,
        (__attribute__((address_space(3))) unsigned int*)l,
        16, 0, 0);
}

__device__ inline ushort_t f2bf(float f) {
    uint32_t u = __float_as_uint(f);
    uint32_t r = (u + 0x7fffu + ((u >> 16) & 1u)) >> 16;
    return (ushort_t)r;
}
__device__ inline float bf2f(ushort_t u) {
    return __uint_as_float((uint32_t)u << 16);
}

// ---------------------------------------------------------------------------
// Generic C = A @ B^T. 128x128 tile, BK=32, XOR-swizzled LDS (conflict-free).
// ---------------------------------------------------------------------------
template <typename OutT>
__global__ __launch_bounds__(256, 2)
void gemm_bt(const ushort_t* __restrict__ A, int lda, long strideA,
             const ushort_t* __restrict__ B, int ldb, long strideB,
             OutT* __restrict__ C0, int ldc0, long strideC0, int K)
{
    __shared__ ushort_t lA[128 * 32];
    __shared__ ushort_t lB[128 * 32];

    const int t    = threadIdx.x;
    const int lane = t & 63;
    const int wid  = t >> 6;
    const int z    = blockIdx.z;

    A += (size_t)z * strideA;
    B += (size_t)z * strideB;

    const int m0 = blockIdx.x * 128;
    const int n0 = blockIdx.y * 128;

    const int wm = (wid >> 1) * 64;
    const int wn = (wid & 1) * 64;
    const int mr = lane & 15;
    const int q4 = lane >> 4;

    const int row_a = t >> 2;
    const int seg   = ((t & 3) ^ ((t >> 3) & 3)) * 8;
    const int csw   = (q4 ^ ((mr >> 1) & 3)) * 16;

    f32x4 acc[4][4] = {};

    for (int k0 = 0; k0 < K; k0 += 32) {
        __syncthreads();
        gld_lds16(A + (size_t)(m0 + row_a) * lda + k0 + seg,      (char*)lA + wid * 1024);
        gld_lds16(A + (size_t)(m0 + 64 + row_a) * lda + k0 + seg, (char*)lA + 4096 + wid * 1024);
        gld_lds16(B + (size_t)(n0 + row_a) * ldb + k0 + seg,      (char*)lB + wid * 1024);
        gld_lds16(B + (size_t)(n0 + 64 + row_a) * ldb + k0 + seg, (char*)lB + 4096 + wid * 1024);
        __syncthreads();

        bf16x8 af[4], bf[4];
#pragma unroll
        for (int i = 0; i < 4; ++i)
            af[i] = *(const bf16x8*)((const char*)lA + (wm + i * 16 + mr) * 64 + csw);
#pragma unroll
        for (int j = 0; j < 4; ++j)
            bf[j] = *(const bf16x8*)((const char*)lB + (wn + j * 16 + mr) * 64 + csw);
#pragma unroll
        for (int i = 0; i < 4; ++i)
#pragma unroll
            for (int j = 0; j < 4; ++j)
                acc[i][j] = __builtin_amdgcn_mfma_f32_16x16x32_bf16(af[i], bf[j], acc[i][j], 0, 0, 0);
    }

    OutT* Cw = C0 + (size_t)z * strideC0;
#pragma unroll
    for (int i = 0; i < 4; ++i) {
        const int rbase = m0 + wm + i * 16 + q4 * 4;
#pragma unroll
        for (int j = 0; j < 4; ++j) {
            const int col = n0 + wn + j * 16 + mr;
#pragma unroll
            for (int r = 0; r < 4; ++r) {
                const float v = acc[i][j][r];
                const size_t off = (size_t)(rbase + r) * ldc0 + col;
                if constexpr (sizeof(OutT) == 2) Cw[off] = f2bf(v);
                else                             Cw[off] = v;
            }
        }
    }
}

// ---------------------------------------------------------------------------
// Gram GEMM: Gp[z] partial of x[b]^T x[b], upper-triangle 128-tiles only.
// grid (16 z fastest -> XCD round-robin, 36 triangle tiles). A = B = xbT.
// z = b*4+ks: columns b*4096 + ks*1024 of xbT [1024][16384].
// ---------------------------------------------------------------------------
__global__ __launch_bounds__(256, 2)
void gemm_gram(const ushort_t* __restrict__ X, ushort_t* __restrict__ Gp)
{
    __shared__ ushort_t lA[128 * 32];
    __shared__ ushort_t lB[128 * 32];

    const int t    = threadIdx.x;
    const int lane = t & 63;
    const int wid  = t >> 6;

    const int z  = blockIdx.x;
    const int bb = z >> 2, ks = z & 3;

    // triangle tile map: row ti has 8-ti tiles (ti<=tj)
    int ti = 0, rem = blockIdx.y;
    while (rem >= 8 - ti) { rem -= 8 - ti; ++ti; }
    const int tj = ti + rem;
    const int m0 = ti * 128;
    const int n0 = tj * 128;

    const ushort_t* A = X + (size_t)bb * 4096 + (size_t)ks * 1024;

    const int wm = (wid >> 1) * 64;
    const int wn = (wid & 1) * 64;
    const int mr = lane & 15;
    const int q4 = lane >> 4;

    const int row_a = t >> 2;
    const int seg   = ((t & 3) ^ ((t >> 3) & 3)) * 8;
    const int csw   = (q4 ^ ((mr >> 1) & 3)) * 16;

    f32x4 acc[4][4] = {};

    for (int k0 = 0; k0 < 1024; k0 += 32) {
        __syncthreads();
        gld_lds16(A + (size_t)(m0 + row_a) * 16384 + k0 + seg,      (char*)lA + wid * 1024);
        gld_lds16(A + (size_t)(m0 + 64 + row_a) * 16384 + k0 + seg, (char*)lA + 4096 + wid * 1024);
        gld_lds16(A + (size_t)(n0 + row_a) * 16384 + k0 + seg,      (char*)lB + wid * 1024);
        gld_lds16(A + (size_t)(n0 + 64 + row_a) * 16384 + k0 + seg, (char*)lB + 4096 + wid * 1024);
        __syncthreads();

        bf16x8 af[4], bf[4];
#pragma unroll
        for (int i = 0; i < 4; ++i)
            af[i] = *(const bf16x8*)((const char*)lA + (wm + i * 16 + mr) * 64 + csw);
#pragma unroll
        for (int j = 0; j < 4; ++j)
            bf[j] = *(const bf16x8*)((const char*)lB + (wn + j * 16 + mr) * 64 + csw);
#pragma unroll
        for (int i = 0; i < 4; ++i)
#pragma unroll
            for (int j = 0; j < 4; ++j)
                acc[i][j] = __builtin_amdgcn_mfma_f32_16x16x32_bf16(af[i], bf[j], acc[i][j], 0, 0, 0);
    }

    ushort_t* Cw = Gp + ((size_t)z << 20);
#pragma unroll
    for (int i = 0; i < 4; ++i) {
        const int rbase = m0 + wm + i * 16 + q4 * 4;
#pragma unroll
        for (int j = 0; j < 4; ++j) {
            const int col = n0 + wn + j * 16 + mr;
#pragma unroll
            for (int r = 0; r < 4; ++r)
                Cw[(size_t)(rbase + r) * 1024 + col] = f2bf(acc[i][j][r]);
        }
    }
}

// ---------------------------------------------------------------------------
// reduce_g_t: G[b][tr*64+r][tc*64+c] = sum_ks Gp[b*4+ks] at source 64-tile
// (sr,sc)=(min,max) -- inside computed upper 128-triangle since
// sr<=sc => sr>>1 <= sc>>1. Lower tiles transpose through LDS (pitch 65).
// grid (256 tiles: tr=bx>>4, tc=bx&15; 4 b), 256 threads.
// ---------------------------------------------------------------------------
__global__ __launch_bounds__(256)
void reduce_g_t(const ushort_t* __restrict__ Gp, ushort_t* __restrict__ G)
{
    __shared__ float acc[64 * 65];

    const int t  = threadIdx.x;
    const int b  = blockIdx.y;
    const int tr = blockIdx.x >> 4, tc = blockIdx.x & 15;
    const int sr = (tr <= tc) ? tr : tc;
    const int sc = (tr <= tc) ? tc : tr;
    const bool flip = tr > tc;

#pragma unroll
    for (int p = 0; p < 4; ++p) {
        const int idx = p * 256 + t;             // ushort4 index 0..1023
        const int r = idx >> 4, c = (idx & 15) * 4;
        float a0 = 0.f, a1 = 0.f, a2 = 0.f, a3 = 0.f;
#pragma unroll
        for (int ksl = 0; ksl < 4; ++ksl) {
            const ushort4 u = *(const ushort4*)&Gp[((size_t)(b * 4 + ksl) << 20)
                                                   + (size_t)(sr * 64 + r) * 1024 + sc * 64 + c];
            a0 += bf2f(u.x); a1 += bf2f(u.y); a2 += bf2f(u.z); a3 += bf2f(u.w);
        }
        acc[r * 65 + c + 0] = a0;
        acc[r * 65 + c + 1] = a1;
        acc[r * 65 + c + 2] = a2;
        acc[r * 65 + c + 3] = a3;
    }
    __syncthreads();

#pragma unroll
    for (int p = 0; p < 4; ++p) {
        const int idx = p * 256 + t;
        const int r = idx >> 4, c = (idx & 15) * 4;
        float v0, v1, v2, v3;
        if (flip) {
            v0 = acc[(c + 0) * 65 + r];
            v1 = acc[(c + 1) * 65 + r];
            v2 = acc[(c + 2) * 65 + r];
            v3 = acc[(c + 3) * 65 + r];
        } else {
            v0 = acc[r * 65 + c + 0];
            v1 = acc[r * 65 + c + 1];
            v2 = acc[r * 65 + c + 2];
            v3 = acc[r * 65 + c + 3];
        }
        ushort4 o;
        o.x = f2bf(v0); o.y = f2bf(v1); o.z = f2bf(v2); o.w = f2bf(v3);
        *(ushort4*)&G[((size_t)b << 20) + (size_t)(tr * 64 + r) * 1024 + tc * 64 + c] = o;
    }
}

// ---------------------------------------------------------------------------
// cast x fp32 [16384][1024] -> xb bf16 + xbT bf16 [1024][16384]
// ---------------------------------------------------------------------------
__global__ __launch_bounds__(256)
void cast_x_t(const float* __restrict__ x, ushort_t* __restrict__ xb,
              ushort_t* __restrict__ xbT)
{
    __shared__ ushort_t lt[64 * 66];
    const int t  = threadIdx.x;
    const int s0 = blockIdx.x * 64;
    const int i0 = blockIdx.y * 64;

#pragma unroll
    for (int c = 0; c < 4; ++c) {
        const int idx = c * 256 + t;
        const int r = idx >> 4, c4 = (idx & 15) * 4;
        const float4 f = *(const float4*)&x[(size_t)(s0 + r) * 1024 + i0 + c4];
        ushort4 o;
        o.x = f2bf(f.x); o.y = f2bf(f.y); o.z = f2bf(f.z); o.w = f2bf(f.w);
        *(ushort4*)&xb[(size_t)(s0 + r) * 1024 + i0 + c4] = o;
        *(uint32_t*)&lt[r * 66 + c4]     = (uint32_t)o.x | ((uint32_t)o.y << 16);
        *(uint32_t*)&lt[r * 66 + c4 + 2] = (uint32_t)o.z | ((uint32_t)o.w << 16);
    }
    __syncthreads();
#pragma unroll
    for (int c = 0; c < 4; ++c) {
        const int idx = c * 256 + t;
        const int ri = idx >> 4, s4 = (idx & 15) * 4;
        ushort4 o;
        o.x = lt[(s4 + 0) * 66 + ri];
        o.y = lt[(s4 + 1) * 66 + ri];
        o.z = lt[(s4 + 2) * 66 + ri];
        o.w = lt[(s4 + 3) * 66 + ri];
        *(ushort4*)&xbT[(size_t)(i0 + ri) * 16384 + s0 + s4] = o;
    }
}

// ---------------------------------------------------------------------------
// cast+transpose Wq fp32 -> wqT bf16
// ---------------------------------------------------------------------------
__global__ __launch_bounds__(256)
void cast_wt(const float* __restrict__ W, ushort_t* __restrict__ WT)
{
    __shared__ ushort_t lt[64 * 66];
    const int t  = threadIdx.x;
    const int r0 = blockIdx.x * 64;
    const int c0 = blockIdx.y * 64;

#pragma unroll
    for (int c = 0; c < 4; ++c) {
        const int idx = c * 256 + t;
        const int r = idx >> 4, c4 = (idx & 15) * 4;
        const float4 f = *(const float4*)&W[(size_t)(r0 + r) * 1024 + c0 + c4];
        ushort4 o;
        o.x = f2bf(f.x); o.y = f2bf(f.y); o.z = f2bf(f.z); o.w = f2bf(f.w);
        *(uint32_t*)&lt[r * 66 + c4]     = (uint32_t)o.x | ((uint32_t)o.y << 16);
        *(uint32_t*)&lt[r * 66 + c4 + 2] = (uint32_t)o.z | ((uint32_t)o.w << 16);
    }
    __syncthreads();
#pragma unroll
    for (int c = 0; c < 4; ++c) {
        const int idx = c * 256 + t;
        const int ri = idx >> 4, s4 = (idx & 15) * 4;
        ushort4 o;
        o.x = lt[(s4 + 0) * 66 + ri];
        o.y = lt[(s4 + 1) * 66 + ri];
        o.z = lt[(s4 + 2) * 66 + ri];
        o.w = lt[(s4 + 3) * 66 + ri];
        *(ushort4*)&WT[(size_t)(c0 + ri) * 1024 + r0 + s4] = o;
    }
}

// ---------------------------------------------------------------------------
// plain cast Wk/Wv fp32 -> bf16
// ---------------------------------------------------------------------------
__global__ __launch_bounds__(256)
void cast_w2(const float* __restrict__ a, const float* __restrict__ b,
             ushort_t* __restrict__ out)
{
    const float* src = (blockIdx.y == 0) ? a : b;
    const int i = (blockIdx.x * 256 + threadIdx.x) * 4;
    const float4 f = *(const float4*)&src[i];
    ushort4 o;
    o.x = f2bf(f.x); o.y = f2bf(f.y); o.z = f2bf(f.z); o.w = f2bf(f.w);
    *(ushort4*)&out[(size_t)blockIdx.y * 1048576 + i] = o;
}

// ---------------------------------------------------------------------------
// kv partials: KVp[is][bh][d][e] = sum_{i-slice} H[b][h64+d][i]*Wv[h64+e][i]
// ---------------------------------------------------------------------------
__global__ __launch_bounds__(256)
void kvblk(const ushort_t* __restrict__ H, const ushort_t* __restrict__ Wv,
           float* __restrict__ KVp)
{
    __shared__ ushort_t sH[64 * 132];
    __shared__ ushort_t sV[64 * 132];

    const int t  = threadIdx.x;
    const int is = blockIdx.x;
    const int bh = blockIdx.y;
    const int b  = bh >> 4, h = bh & 15;

    const ushort_t* Hp = H + ((size_t)b << 20) + (size_t)(h * 64) * 1024 + is * 128;
    const ushort_t* Vp = Wv + (size_t)(h * 64) * 1024 + is * 128;

#pragma unroll
    for (int i2 = 0; i2 < 8; ++i2) {
        const int ci = i2 * 256 + t;
        const int r = ci >> 5, c = (ci & 31) * 4;
        *(uint2*)&sH[r * 132 + c] = *(const uint2*)&Hp[(size_t)r * 1024 + c];
        *(uint2*)&sV[r * 132 + c] = *(const uint2*)&Vp[(size_t)r * 1024 + c];
    }
    __syncthreads();

    const int d0 = (t >> 4) * 4;
    const int e0 = (t & 15) * 4;
    float acc[4][4] = {};

#pragma unroll 2
    for (int i4 = 0; i4 < 128; i4 += 4) {
        uint2 hu[4], vu[4];
#pragma unroll
        for (int j = 0; j < 4; ++j) {
            hu[j] = *(const uint2*)&sH[(d0 + j) * 132 + i4];
            vu[j] = *(const uint2*)&sV[(e0 + j) * 132 + i4];
        }
        float hf[4][4], vf[4][4];
#pragma unroll
        for (int j = 0; j < 4; ++j) {
            hf[j][0] = __uint_as_float(hu[j].x << 16);
            hf[j][1] = __uint_as_float(hu[j].x & 0xffff0000u);
            hf[j][2] = __uint_as_float(hu[j].y << 16);
            hf[j][3] = __uint_as_float(hu[j].y & 0xffff0000u);
            vf[j][0] = __uint_as_float(vu[j].x << 16);
            vf[j][1] = __uint_as_float(vu[j].x & 0xffff0000u);
            vf[j][2] = __uint_as_float(vu[j].y << 16);
            vf[j][3] = __uint_as_float(vu[j].y & 0xffff0000u);
        }
#pragma unroll
        for (int ii = 0; ii < 4; ++ii)
#pragma unroll
            for (int di = 0; di < 4; ++di)
#pragma unroll
                for (int ej = 0; ej < 4; ++ej)
                    acc[di][ej] += hf[di][ii] * vf[ej][ii];
    }

    float* outp = KVp + ((size_t)(is * 64 + bh)) * 4096;
#pragma unroll
    for (int i = 0; i < 4; ++i) {
        float4 o; o.x = acc[i][0]; o.y = acc[i][1]; o.z = acc[i][2]; o.w = acc[i][3];
        *(float4*)&outp[(d0 + i) * 64 + e0] = o;
    }
}

// ---------------------------------------------------------------------------
__global__ __launch_bounds__(256)
void reduce_kv8(const float4* __restrict__ in, float4* __restrict__ out)
{
    const int i = blockIdx.x * 256 + threadIdx.x;
    float4 a = in[i];
#pragma unroll
    for (int s = 1; s < 8; ++s) {
        const float4 b = in[s * 65536 + i];
        a.x += b.x; a.y += b.y; a.z += b.z; a.w += b.w;
    }
    out[i] = a;
}

// ---------------------------------------------------------------------------
// E_t[b][j][h*64+d] = scale * sum_e kv[b,h,d,e] * W_o[j, h*64+e]
// ---------------------------------------------------------------------------
__global__ __launch_bounds__(256)
void make_E(const float* __restrict__ KV, const float* __restrict__ Wo,
            ushort_t* __restrict__ Et)
{
    __shared__ float skv[64 * 65];
    __shared__ float swo[64 * 65];

    const int t  = threadIdx.x;
    const int bh = blockIdx.y;
    const int b  = bh >> 4, h = bh & 15;
    const int j0 = blockIdx.x * 64;

    const float* kvp = KV + (size_t)bh * 4096;
#pragma unroll
    for (int i = 0; i < 4; ++i) {
        const int idx = t + i * 256;
        const int r = idx >> 4, c = (idx & 15) * 4;
        const float4 f = *(const float4*)&kvp[r * 64 + c];
        skv[r * 65 + c + 0] = f.x;
        skv[r * 65 + c + 1] = f.y;
        skv[r * 65 + c + 2] = f.z;
        skv[r * 65 + c + 3] = f.w;
        const float4 g = *(const float4*)&Wo[(size_t)(j0 + r) * 1024 + h * 64 + c];
        swo[r * 65 + c + 0] = g.x;
        swo[r * 65 + c + 1] = g.y;
        swo[r * 65 + c + 2] = g.z;
        swo[r * 65 + c + 3] = g.w;
    }
    __syncthreads();

    const int d0 = (t & 15) * 4;
#pragma unroll
    for (int pass = 0; pass < 4; ++pass) {
        const int jloc = (t >> 4) + pass * 16;
        float s0 = 0.f, s1 = 0.f, s2 = 0.f, s3 = 0.f;
        const float* wrow = &swo[jloc * 65];
#pragma unroll 8
        for (int e = 0; e < 64; ++e) {
            const float w = wrow[e];
            s0 += skv[(d0 + 0) * 65 + e] * w;
            s1 += skv[(d0 + 1) * 65 + e] * w;
            s2 += skv[(d0 + 2) * 65 + e] * w;
            s3 += skv[(d0 + 3) * 65 + e] * w;
        }
        ushort4 o;
        o.x = f2bf(s0 * 0.125f);
        o.y = f2bf(s1 * 0.125f);
        o.z = f2bf(s2 * 0.125f);
        o.w = f2bf(s3 * 0.125f);
        *(ushort4*)&Et[((size_t)b * 1024 + j0 + jloc) * 1024 + h * 64 + d0] = o;
    }
}

// ---------------------------------------------------------------------------

extern "C" void kernel_launch(void* const* d_in, const int* in_sizes, int n_in,
                              void* d_out, int out_size, void* d_ws, size_t ws_size,
                              hipStream_t stream)
{
    const float* x  = (const float*)d_in[0];
    const float* Wq = (const float*)d_in[1];
    const float* Wk = (const float*)d_in[2];
    const float* Wv = (const float*)d_in[3];
    const float* Wo = (const float*)d_in[4];
    float* out = (float*)d_out;

    const int B = 4, S = 4096, D = 1024;
    const long MB1 = 1048576;

    char* ws = (char*)d_ws;
    size_t off = 0;
    auto alloc = [&](size_t bytes) -> void* {
        void* p = ws + off;
        off += (bytes + 255) & ~(size_t)255;
        return p;
    };
    ushort_t* xb   = (ushort_t*)alloc((size_t)B * S * D * 2);      // 33.5 MB
    ushort_t* xbT  = (ushort_t*)alloc((size_t)D * B * S * 2);      // 33.5 MB
    ushort_t* wkv  = (ushort_t*)alloc((size_t)2 * D * D * 2);      // wk | wv
    ushort_t* wqT  = (ushort_t*)alloc((size_t)D * D * 2);
    ushort_t* Gb   = (ushort_t*)alloc((size_t)B * D * D * 2);      // 8.4 MB
    float*    kvp  = (float*)alloc((size_t)8 * 64 * 4096 * 4);     // 8.4 MB
    float*    kvr  = (float*)alloc((size_t)64 * 4096 * 4);         // 1 MB
    ushort_t* Fb   = (ushort_t*)alloc((size_t)B * D * D * 2);      // 8.4 MB (own slab!)
    char*     R1   = (char*)alloc((size_t)16 * MB1 * 2);           // 33.5 MB shared
    ushort_t* Gp = (ushort_t*)R1;                    // [16][1M] bf16 partials
    ushort_t* Hb = (ushort_t*)R1;                    // [4][1M] (Gp[0..7] dead after reduce)
    ushort_t* Et = (ushort_t*)(R1 + 8 * MB1 * 2);    // [4][1M] (Gp[8..15] dead after reduce)
    ushort_t* wkb = wkv;
    ushort_t* wvb = wkv + MB1;

    // casts
    cast_x_t<<<dim3(256, 16), dim3(256), 0, stream>>>(x, xb, xbT);
    cast_w2<<<dim3(1024, 2), dim3(256), 0, stream>>>(Wk, Wv, wkv);
    cast_wt<<<dim3(16, 16), dim3(256), 0, stream>>>(Wq, wqT);

    // G[b] = x^T x, symmetric: 36 upper-triangle 128-tiles, split-K=4, z fastest
    gemm_gram<<<dim3(16, 36), dim3(256), 0, stream>>>(xbT, Gp);
    reduce_g_t<<<dim3(256, 4), dim3(256), 0, stream>>>(Gp, Gb);

    // H[b] = Wk @ G[b]  (G symmetric -> use as B directly)
    gemm_bt<ushort_t><<<dim3(8, 8, 4), dim3(256), 0, stream>>>(
        wkb, D, 0, Gb, D, MB1, Hb, D, MB1, D);

    // kv[b,h] = H_h @ Wv_h^T (i-split 8) + reduce
    kvblk<<<dim3(8, 64), dim3(256), 0, stream>>>(Hb, wvb, kvp);
    reduce_kv8<<<dim3(256), dim3(256), 0, stream>>>((const float4*)kvp, (float4*)kvr);

    // E_t
    make_E<<<dim3(16, 64), dim3(256), 0, stream>>>(kvr, Wo, Et);

    // F[b] = E_t[b] @ Wq
    gemm_bt<ushort_t><<<dim3(8, 8, 4), dim3(256), 0, stream>>>(
        Et, D, MB1, wqT, D, 0, Fb, D, (long)D * D, D);

    // out[b] = x[b] @ F[b]^T -> fp32
    gemm_bt<float><<<dim3(32, 8, 4), dim3(256), 0, stream>>>(
        xb, D, (long)S * D, Fb, D, (long)D * D, out, D, (long)S * D, D);
}